// Round 2
// baseline (271.436 us; speedup 1.0000x reference)
//
#include <hip/hip_runtime.h>
#include <hip/hip_bf16.h>
#include <math.h>

#define N 8192
#define M 8192
#define D 64

typedef __bf16 bf16x8 __attribute__((ext_vector_type(8)));
typedef float f32x4 __attribute__((ext_vector_type(4)));

// ---------------------------------------------------------------------------
// Prep: split fp32 rows into bf16 hi/lo + fp32 row norms, stored in
// MFMA-fragment order (dense 1 KB loads in the main kernel). Unchanged.
// ---------------------------------------------------------------------------
__global__ __launch_bounds__(256) void prep_kernel(
    const float* __restrict__ x, const float* __restrict__ y,
    __bf16* __restrict__ xsh, __bf16* __restrict__ xsl, float* __restrict__ xn,
    __bf16* __restrict__ ysh, __bf16* __restrict__ ysl, float* __restrict__ yn)
{
    int t   = threadIdx.x;
    int row = blockIdx.x * 32 + (t >> 3);
    int c   = t & 7;                       // chunk: k = c>>2, quad = c&3

    const float* src;
    __bf16 *ph, *pl;
    float* nrm;
    int r;
    bool isx = row < N;
    if (isx) { src = x; ph = xsh; pl = xsl; nrm = xn; r = row; }
    else     { src = y; ph = ysh; pl = ysl; nrm = yn; r = row - N; }

    const float* p = src + (size_t)r * D + c * 8;
    f32x4 a = *reinterpret_cast<const f32x4*>(p);
    f32x4 b = *reinterpret_cast<const f32x4*>(p + 4);
    float v[8] = {a[0], a[1], a[2], a[3], b[0], b[1], b[2], b[3]};

    bf16x8 hv, lv;
    float s = 0.0f;
    #pragma unroll
    for (int i = 0; i < 8; ++i) {
        float vi = v[i];
        __bf16 hi = (__bf16)vi;            // RNE round to bf16
        float lof = vi - (float)hi;        // exact residual
        hv[i] = hi;
        lv[i] = (__bf16)lof;
        s += vi * vi;
    }
    s += __shfl_down(s, 4);
    s += __shfl_down(s, 2);
    s += __shfl_down(s, 1);

    int g = r >> 6, m = r & 63;
    int slot;
    if (isx) slot = ((m >> 4) * 2 + (c >> 2)) * 64 + (c & 3) * 16 + (m & 15);
    else     slot = ((m & 3)  * 2 + (c >> 2)) * 64 + (c & 3) * 16 + (m >> 2);
    size_t idx = (size_t)g * 4096 + (size_t)slot * 8;

    *reinterpret_cast<bf16x8*>(ph + idx) = hv;
    *reinterpret_cast<bf16x8*>(pl + idx) = lv;
    if (c == 0) nrm[r] = s;
}

// ---------------------------------------------------------------------------
// Main, R2: write-stream page locality.
// Block tile = 128 rows x 1024 cols (j-loop over 8 steps of 64 cols).
// Per wave: 64 rows x 512 cols. Grid = (8,64) = 512 blocks, all co-resident
// at 2 waves/SIMD (__launch_bounds__(256,2) -> VGPR cap 256, room for B dbuf).
//
// Rationale: R1 proved NT-vs-plain stores neutral, so the ~4.3 TB/s write cap
// (vs 6.4 TB/s fill on the same path) is address-pattern: 128-col tiles give
// each DRAM channel only 512 B sequential runs per row-stream. 1024-col
// blocks give 4 KB runs (several full HBM pages) and halve resident streams.
// Fill proves <1 wave/SIMD saturates write BW, so occupancy drop is safe;
// MFMA (~12 us total) hides under the write drain.
//
// B fragments: explicit register double-buffer (issue next group's loads
// before computing current). A fragments streamed per-ti (L1/L2 hits).
// Inner math/epilogue identical to R1 -> absmax unchanged.
// C/D: n = lane&15, m = quad*4 + reg  (verified m89/m91); B col = j+4*l16+t.
// ---------------------------------------------------------------------------
__global__ __launch_bounds__(256, 2) void rbf_kernel(
    const __bf16* __restrict__ xsh, const __bf16* __restrict__ xsl,
    const float* __restrict__ xn,
    const __bf16* __restrict__ ysh, const __bf16* __restrict__ ysl,
    const float* __restrict__ yn,
    const float* __restrict__ sig, float* __restrict__ out)
{
    int tid  = threadIdx.x;
    int wave = tid >> 6;
    int lane = tid & 63;
    int quad = lane >> 4;
    int l16  = lane & 15;

    int i_base = blockIdx.y * 128 + (wave >> 1) * 64;
    int j0     = blockIdx.x * 1024 + (wave & 1) * 512;

    float s = sig[0];
    const float log2e = 1.4426950408889634f;
    float c  = -0.5f / (s * s) * log2e;    // < 0
    float c2 = -2.0f * c;

    // A base pointers (one 64-row group per wave), loads streamed per ti.
    const __bf16* pah = xsh + (size_t)(i_base >> 6) * 4096 + lane * 8;
    const __bf16* pal = xsl + (size_t)(i_base >> 6) * 4096 + lane * 8;

    // x norms resident across the whole j loop (16 VGPRs).
    f32x4 xnv[4];
    #pragma unroll
    for (int ti = 0; ti < 4; ++ti)
        xnv[ti] = *reinterpret_cast<const f32x4*>(xn + i_base + ti * 16 + quad * 4);

    // B double buffer: current + next group (64+64 VGPRs).
    const __bf16* pbh = ysh + (size_t)(j0 >> 6) * 4096 + lane * 8;
    const __bf16* pbl = ysl + (size_t)(j0 >> 6) * 4096 + lane * 8;

    bf16x8 BHc[4][2], BLc[4][2];
    #pragma unroll
    for (int t = 0; t < 4; ++t)
        #pragma unroll
        for (int k = 0; k < 2; ++k) {
            BHc[t][k] = *reinterpret_cast<const bf16x8*>(pbh + (t * 2 + k) * 512);
            BLc[t][k] = *reinterpret_cast<const bf16x8*>(pbl + (t * 2 + k) * 512);
        }
    f32x4 ynv = *reinterpret_cast<const f32x4*>(yn + j0 + 4 * l16);

    #pragma unroll
    for (int jt = 0; jt < 8; ++jt) {
        int j = j0 + jt * 64;

        // Prefetch next B group early (overlaps with this step's MFMAs).
        bf16x8 BHn[4][2], BLn[4][2];
        f32x4 ynvn;
        if (jt < 7) {
            const __bf16* nbh = pbh + (size_t)(jt + 1) * 4096;
            const __bf16* nbl = pbl + (size_t)(jt + 1) * 4096;
            #pragma unroll
            for (int t = 0; t < 4; ++t)
                #pragma unroll
                for (int k = 0; k < 2; ++k) {
                    BHn[t][k] = *reinterpret_cast<const bf16x8*>(nbh + (t * 2 + k) * 512);
                    BLn[t][k] = *reinterpret_cast<const bf16x8*>(nbl + (t * 2 + k) * 512);
                }
            ynvn = *reinterpret_cast<const f32x4*>(yn + j + 64 + 4 * l16);
        }

        #pragma unroll
        for (int ti = 0; ti < 4; ++ti) {
            bf16x8 Ah[2], Al[2];
            #pragma unroll
            for (int k = 0; k < 2; ++k) {
                Ah[k] = *reinterpret_cast<const bf16x8*>(pah + (ti * 2 + k) * 512);
                Al[k] = *reinterpret_cast<const bf16x8*>(pal + (ti * 2 + k) * 512);
            }

            f32x4 acc[4];
            #pragma unroll
            for (int t = 0; t < 4; ++t) acc[t] = (f32x4){0.f, 0.f, 0.f, 0.f};

            #pragma unroll
            for (int k = 0; k < 2; ++k)
                #pragma unroll
                for (int t = 0; t < 4; ++t) {
                    acc[t] = __builtin_amdgcn_mfma_f32_16x16x32_bf16(Ah[k], BHc[t][k], acc[t], 0, 0, 0);
                    acc[t] = __builtin_amdgcn_mfma_f32_16x16x32_bf16(Ah[k], BLc[t][k], acc[t], 0, 0, 0);
                    acc[t] = __builtin_amdgcn_mfma_f32_16x16x32_bf16(Al[k], BHc[t][k], acc[t], 0, 0, 0);
                }

            #pragma unroll
            for (int r = 0; r < 4; ++r) {
                int row = i_base + ti * 16 + quad * 4 + r;
                f32x4 v;
                #pragma unroll
                for (int t = 0; t < 4; ++t) {
                    float arg = __builtin_fmaf(c2, acc[t][r], c * (xnv[ti][r] + ynv[t]));
                    arg = fminf(arg, 0.0f);
                    v[t] = __builtin_amdgcn_exp2f(arg);
                }
                *reinterpret_cast<f32x4*>(out + (size_t)row * M + j + 4 * l16) = v;
            }
        }

        // Rotate double buffer (static under full unroll -> pure renames).
        if (jt < 7) {
            #pragma unroll
            for (int t = 0; t < 4; ++t)
                #pragma unroll
                for (int k = 0; k < 2; ++k) {
                    BHc[t][k] = BHn[t][k];
                    BLc[t][k] = BLn[t][k];
                }
            ynv = ynvn;
        }
    }
}

extern "C" void kernel_launch(void* const* d_in, const int* in_sizes, int n_in,
                              void* d_out, int out_size, void* d_ws, size_t ws_size,
                              hipStream_t stream) {
    const float* x   = (const float*)d_in[0];
    const float* y   = (const float*)d_in[1];
    const float* sig = (const float*)d_in[2];
    float* out = (float*)d_out;

    char* ws = (char*)d_ws;
    __bf16* xsh = (__bf16*)(ws);
    __bf16* xsl = (__bf16*)(ws + (1u << 20));
    __bf16* ysh = (__bf16*)(ws + (2u << 20));
    __bf16* ysl = (__bf16*)(ws + (3u << 20));
    float*  xn  = (float*) (ws + (4u << 20));
    float*  yn  = (float*) (ws + (4u << 20) + (1u << 15));

    prep_kernel<<<(N + M) / 32, 256, 0, stream>>>(x, y, xsh, xsl, xn, ysh, ysl, yn);

    dim3 grid(M / 1024, N / 128);
    rbf_kernel<<<grid, 256, 0, stream>>>(xsh, xsl, xn, ysh, ysl, yn, sig, out);
}